// Round 1
// baseline (188.460 us; speedup 1.0000x reference)
//
#include <hip/hip_runtime.h>
#include <hip/hip_bf16.h>

// BatchedNLM: per-neuron 2-layer GLU MLP.
//   state_trace (128,2048,32) f32, fc1_w (2048,32,256), fc1_b (2048,256),
//   fc2_w (2048,128,2), fc2_b (2048,2), T (1)  ->  out (128,2048) f32
//
// One block per neuron. 256 threads = 4 waves; wave w owns batches [32w,32w+32).
// GEMM1 via mfma_f32_16x16x32_bf16 (K=32 in a single MFMA).
// GLU1 pairs (h, h+128) = tiles (p, p+8): same lane, same acc reg -> register-only.
// fc2 (K=128, N=2) folded into the tile loop as per-lane partials + shfl_xor tree.
//
// R2: coalesced 512B row into out_t (2048,128) in d_ws + transpose kernel.
// R3: __launch_bounds__(256,4) — (256,8) forced VGPR 64->32 + 500 MB spills.
// R4 FAILED: register-batching w1 loads under 64-VGPR cap -> spills.
// R5 WIN (94->46 us): w1 via global_load_lds width=16 (async DMA, no VGPRs).
// R6: rcp-sigmoid + ldsB aliased onto ldsW (LDS 51.7->35.3 KB).
// R7 (this): counters showed nlm <41us but Occ ~18% ~= 2 blocks/CU -> VGPR>128
//     suspected (launch_bounds(256,2) allows 256). Also the DMA path forced
//     3 barriers + a 32-reg cross-barrier staging array + 16 KB extra LDS.
//     -> direct coalesced column loads (thread t owns h=t, 32 stride-1KB
//     dwords, chunked convert, fragment-major ds_write_b128), ONE barrier,
//     LDS 35.3->18.9 KB, __launch_bounds__(256,4) caps VGPR at 128.
//     Also: fc1 bias folded into MFMA C-operand init.

#define NN 2048

typedef __attribute__((ext_vector_type(8))) short short8;
typedef __attribute__((ext_vector_type(4))) float floatx4;
typedef __attribute__((ext_vector_type(4))) int int4v;

static __device__ __forceinline__ unsigned int pkbf(float a, float b) {
    __hip_bfloat162 h = __float22bfloat162_rn(make_float2(a, b));  // v_cvt_pk_bf16_f32
    return *(unsigned int*)&h;
}

static __device__ __forceinline__ float sigmoidf_(float x) {
    // v_mul + v_exp + v_add + v_rcp (NOT the IEEE div sequence)
    return __builtin_amdgcn_rcpf(1.0f + __expf(-x));
}

__global__ __launch_bounds__(256, 4)
void nlm_kernel(const float* __restrict__ st,
                const float* __restrict__ w1,
                const float* __restrict__ b1,
                const float* __restrict__ w2,
                const float* __restrict__ b2,
                const float* __restrict__ Tp,
                float* __restrict__ out_t)
{
    const int n = blockIdx.x;
    const int t = threadIdx.x;

    __shared__ __align__(16) short ldsB[8192];  // 16 KB bf16 W1, fragment-major
    __shared__ float4 ldsP[128];    // {b1[h], b1[128+h], w2[2h], w2[2h+1]}
    __shared__ float  ldsO[128];

    const int lane = t & 63;
    const int wv   = t >> 6;      // wave 0..3
    const int m    = lane & 15;   // A row / C col
    const int quad = lane >> 4;   // k-quad / C row group

    // ---- 1) A-fragments (st): issue first, 2x16B per thread ----
    floatx4 av[2][2];
    #pragma unroll
    for (int bt = 0; bt < 2; ++bt) {
        const int b = wv * 32 + bt * 16 + m;
        const float* sp = st + (size_t)b * (NN * 32) + (size_t)n * 32 + quad * 8;
        av[bt][0] = *(const floatx4*)sp;
        av[bt][1] = *(const floatx4*)(sp + 4);
    }

    // ---- 2) Param table ----
    const float* b1p = b1 + n * 256;
    const float* w2p = w2 + n * 256;
    if (t < 128) {
        float  pba = b1p[t];
        float  pbb = b1p[128 + t];
        float2 pw2 = *(const float2*)(w2p + 2 * t);
        ldsP[t] = make_float4(pba, pbb, pw2.x, pw2.y);
    }

    const float bb0  = b2[n * 2 + 0];
    const float bb1  = b2[n * 2 + 1];
    const float invT = 1.0f / Tp[0];

    // ---- 3) W1 column load + convert: thread t owns column h=t. ----
    // 32 dword loads at stride 256 floats; across lanes consecutive t ->
    // consecutive addresses -> fully coalesced 256B/instr. Converted in 4
    // chunks of 8 (limits liveness to ~12 regs) and written fragment-major:
    // short idx = (h>>4)*512 + (k>>3)*128 + (h&15)*8 + (k&7).
    {
        const float* gW = w1 + (size_t)n * 8192 + t;
        const int base = ((t >> 4) * 512) + ((t & 15) * 8);
        #pragma unroll
        for (int q = 0; q < 4; ++q) {
            float wq[8];
            #pragma unroll
            for (int e = 0; e < 8; ++e)
                wq[e] = gW[(q * 8 + e) * 256];
            union { int4v i; short8 s; } u;
            #pragma unroll
            for (int e = 0; e < 4; ++e)
                u.i[e] = pkbf(wq[2 * e], wq[2 * e + 1]);
            // lanes 0..15 hit byte offsets (t&15)*16 -> 2-way bank alias (free)
            *(short8*)&ldsB[base + q * 128] = u.s;
        }
    }

    // Convert A-frags while W1 stores drain.
    short8 afrag[2];
    #pragma unroll
    for (int bt = 0; bt < 2; ++bt) {
        union { int4v i; short8 s; } u;
        u.i[0] = pkbf(av[bt][0][0], av[bt][0][1]);
        u.i[1] = pkbf(av[bt][0][2], av[bt][0][3]);
        u.i[2] = pkbf(av[bt][1][0], av[bt][1][1]);
        u.i[3] = pkbf(av[bt][1][2], av[bt][1][3]);
        afrag[bt] = u.s;
    }

    __syncthreads();   // the ONLY staging barrier

    // ---- 4) Compute: 8 tile-pairs, fc1 bias in MFMA acc, fc2 folded in ----
    float pacc[2][4][2];
    #pragma unroll
    for (int bt = 0; bt < 2; ++bt)
        #pragma unroll
        for (int r = 0; r < 4; ++r)
            pacc[bt][r][0] = pacc[bt][r][1] = 0.0f;

    #pragma unroll
    for (int p = 0; p < 8; ++p) {
        short8 bfA = *(short8*)&ldsB[(p * 64 + lane) * 8];
        short8 bfB = *(short8*)&ldsB[((p + 8) * 64 + lane) * 8];
        float4 prm = ldsP[p * 16 + m];   // {bias_a, bias_b, w2a, w2b} for h=p*16+m
        floatx4 ca = {prm.x, prm.x, prm.x, prm.x};   // per-col bias as C-init
        floatx4 cb = {prm.y, prm.y, prm.y, prm.y};

        #pragma unroll
        for (int bt = 0; bt < 2; ++bt) {
            floatx4 xa = __builtin_amdgcn_mfma_f32_16x16x32_bf16(afrag[bt], bfA, ca, 0, 0, 0);
            floatx4 xb = __builtin_amdgcn_mfma_f32_16x16x32_bf16(afrag[bt], bfB, cb, 0, 0, 0);
            #pragma unroll
            for (int r = 0; r < 4; ++r) {
                float glu = xa[r] * sigmoidf_(xb[r]);
                pacc[bt][r][0] += glu * prm.z;
                pacc[bt][r][1] += glu * prm.w;
            }
        }
    }

    // ---- 5) Reduce fc2 partials across the 16 lanes of each quad ----
    #pragma unroll
    for (int bt = 0; bt < 2; ++bt) {
        #pragma unroll
        for (int r = 0; r < 4; ++r) {
            float s0 = pacc[bt][r][0];
            float s1 = pacc[bt][r][1];
            s0 += __shfl_xor(s0, 1);  s1 += __shfl_xor(s1, 1);
            s0 += __shfl_xor(s0, 2);  s1 += __shfl_xor(s1, 2);
            s0 += __shfl_xor(s0, 4);  s1 += __shfl_xor(s1, 4);
            s0 += __shfl_xor(s0, 8);  s1 += __shfl_xor(s1, 8);
            if (m == 0) {
                const int b = wv * 32 + bt * 16 + quad * 4 + r;
                float x0 = s0 + bb0;
                float x1 = s1 + bb1;
                ldsO[b] = x0 * sigmoidf_(x1) * invT;
            }
        }
    }

    __syncthreads();

    // One coalesced 512B row per block into out_t (2048,128).
    if (t < 128)
        out_t[(size_t)n * 128 + t] = ldsO[t];
}

// Transpose out_t (2048,128) -> out (128,2048). 32x32 tiles, 256 blocks.
__global__ __launch_bounds__(256)
void transpose_kernel(const float* __restrict__ out_t, float* __restrict__ out)
{
    __shared__ float tile[32][33];
    const int t    = threadIdx.x;
    const int bidx = blockIdx.x;           // 0..255
    const int n0   = (bidx & 63) * 32;     // 64 n-tiles
    const int b0   = (bidx >> 6) * 32;     // 4 b-tiles

    const int tx = t & 31;
    const int ty = t >> 5;                 // 0..7

    #pragma unroll
    for (int i = 0; i < 4; ++i) {
        const int nl = ty + i * 8;
        tile[nl][tx] = out_t[(size_t)(n0 + nl) * 128 + b0 + tx];
    }

    __syncthreads();

    #pragma unroll
    for (int i = 0; i < 4; ++i) {
        const int bl = ty + i * 8;
        out[(size_t)(b0 + bl) * NN + n0 + tx] = tile[tx][bl];
    }
}

extern "C" void kernel_launch(void* const* d_in, const int* in_sizes, int n_in,
                              void* d_out, int out_size, void* d_ws, size_t ws_size,
                              hipStream_t stream) {
    const float* st = (const float*)d_in[0];
    const float* w1 = (const float*)d_in[1];
    const float* b1 = (const float*)d_in[2];
    const float* w2 = (const float*)d_in[3];
    const float* b2 = (const float*)d_in[4];
    const float* T  = (const float*)d_in[5];
    float* out   = (float*)d_out;
    float* out_t = (float*)d_ws;    // 2048*128*4 = 1 MB scratch

    nlm_kernel<<<dim3(NN), dim3(256), 0, stream>>>(st, w1, b1, w2, b2, T, out_t);
    transpose_kernel<<<dim3(256), dim3(256), 0, stream>>>(out_t, out);
}

// Round 2
// 131.460 us; speedup vs baseline: 1.4336x; 1.4336x over previous
//
#include <hip/hip_runtime.h>
#include <hip/hip_bf16.h>

// BatchedNLM: per-neuron 2-layer GLU MLP.
//   state_trace (128,2048,32) f32, fc1_w (2048,32,256), fc1_b (2048,256),
//   fc2_w (2048,128,2), fc2_b (2048,2), T (1)  ->  out (128,2048) f32
//
// One block per neuron. R8: 512 threads = 8 waves; wave w owns batches [16w,16w+16).
// GEMM1 via mfma_f32_16x16x32_bf16 (K=32 in a single MFMA).
// GLU1 pairs (h, h+128) = tiles (p, p+8): same lane, same acc reg -> register-only.
// fc2 (K=128, N=2) folded into the tile loop as per-lane partials + shfl_xor tree.
//
// R2: coalesced 512B row into out_t (2048,128) in d_ws + transpose kernel.
// R3: __launch_bounds__ history: (256,8) forced VGPR 64->32 + 500 MB spills.
// R4 FAILED: register-batching w1 loads under 64-VGPR cap -> spills.
// R5 WIN (94->46 us): w1 via global_load_lds width=16 (async DMA, no VGPRs).
// R6 (~40us): rcp-sigmoid + ldsB aliased onto ldsW (LDS 51.7->35.3 KB).
// R7 FAILED (nlm 90us): replaced DMA with 32-reg column loads under (256,4);
//     compiler hoisted all 32 loads -> spilled ~56 dwords/thread ->
//     WRITE_SIZE 113 MB of scratch traffic, kernel traffic-bound at 2.6 TB/s.
//     Lesson: register-staging w1 ALWAYS spills (R4 confirmed); keep DMA.
// R8 (this): R6 structure + 512 threads/block (8 waves x 16 batches).
//     Halves per-wave work/VGPR; LDS 35.3 KB -> 4 blocks/CU -> 32 waves/CU
//     theoretical (was 16). More waves cover the vmcnt(0) DMA drain + the
//     scattered st gather. Also fc1 bias folded into MFMA C-operand (R7's
//     one good bit).

#define NN 2048

typedef __attribute__((ext_vector_type(8))) short short8;
typedef __attribute__((ext_vector_type(4))) float floatx4;
typedef __attribute__((ext_vector_type(4))) int int4v;

static __device__ __forceinline__ unsigned int pkbf(float a, float b) {
    __hip_bfloat162 h = __float22bfloat162_rn(make_float2(a, b));  // v_cvt_pk_bf16_f32
    return *(unsigned int*)&h;
}

static __device__ __forceinline__ float sigmoidf_(float x) {
    // v_mul + v_exp + v_add + v_rcp (NOT the IEEE div sequence)
    return __builtin_amdgcn_rcpf(1.0f + __expf(-x));
}

static __device__ __forceinline__ void gload_lds16(const float* g, float* l) {
    // Per-lane gptr; LDS dest = wave-uniform base + lane*16B (m97/m104 semantics).
    __builtin_amdgcn_global_load_lds((const __attribute__((address_space(1))) void*)g,
                                     (__attribute__((address_space(3))) void*)l,
                                     16, 0, 0);
}

__global__ __launch_bounds__(512, 4)
void nlm_kernel(const float* __restrict__ st,
                const float* __restrict__ w1,
                const float* __restrict__ b1,
                const float* __restrict__ w2,
                const float* __restrict__ b2,
                const float* __restrict__ Tp,
                float* __restrict__ out_t)
{
    const int n = blockIdx.x;
    const int t = threadIdx.x;     // 0..511

    // ldsW: raw f32 W1[n] (32 KB). After the register-held conversion pass its
    // first 16 KB is REUSED as the fragment-major bf16 buffer (ldsB).
    __shared__ __align__(16) float  ldsW[32 * 256];
    __shared__ float4 ldsP[128];          // {b1[h], b1[128+h], w2[2h], w2[2h+1]}
    __shared__ float  ldsO[128];
    short* ldsB = (short*)ldsW;

    const int lane = t & 63;
    const int wv   = t >> 6;      // wave 0..7
    const int m    = lane & 15;   // A row / C col
    const int quad = lane >> 4;   // k-quad / C row group

    // ---- 1) Async DMA: W1[n] (32 KB f32) -> ldsW. 4 instrs/wave, no VGPRs. ----
    {
        const float* gW = w1 + (size_t)n * 8192;
        #pragma unroll
        for (int i = 0; i < 4; ++i) {
            const int off = wv * 1024 + i * 256;      // floats, wave-uniform
            gload_lds16(gW + off + lane * 4, &ldsW[off]);
        }
    }

    // ---- 2) Register loads issued behind the DMA: A-frag + param table ----
    floatx4 av[2];
    {
        const int b = wv * 16 + m;
        const float* sp = st + (size_t)b * (NN * 32) + (size_t)n * 32 + quad * 8;
        av[0] = *(const floatx4*)sp;
        av[1] = *(const floatx4*)(sp + 4);
    }

    if (t < 128) {
        const float* b1p = b1 + n * 256;
        const float* w2p = w2 + n * 256;
        float  pba = b1p[t];
        float  pbb = b1p[128 + t];
        float2 pw2 = *(const float2*)(w2p + 2 * t);
        ldsP[t] = make_float4(pba, pbb, pw2.x, pw2.y);
    }

    const float bb0  = b2[n * 2 + 0];
    const float bb1  = b2[n * 2 + 1];
    const float invT = 1.0f / Tp[0];

    // Convert A-frag while DMA is in flight.
    short8 afrag;
    {
        union { int4v i; short8 s; } u;
        u.i[0] = pkbf(av[0][0], av[0][1]);
        u.i[1] = pkbf(av[0][2], av[0][3]);
        u.i[2] = pkbf(av[1][0], av[1][1]);
        u.i[3] = pkbf(av[1][2], av[1][3]);
        afrag = u.s;
    }

    __syncthreads();   // drains DMA (vmcnt) + LDS writes

    // ---- 3) In-place conversion: ldsW f32 -> registers -> ldsB bf16 ----
    // Thread t owns column h = t&255, k-range [(t>>8)*16, +16). Reads
    // ldsW[k*256+h]: lanes consecutive -> 2-way bank alias = free. All reads
    // complete (barrier) before the bf16 overwrite of the first 16 KB.
    float w[16];
    const int h  = t & 255;
    const int kb = (t >> 8) * 16;
    #pragma unroll
    for (int k = 0; k < 16; ++k)
        w[k] = ldsW[(kb + k) * 256 + h];

    __syncthreads();   // everyone done reading f32 before bf16 overwrite

    {
        // fragment-major short idx = (h>>4)*512 + (k>>3)*128 + (h&15)*8 + (k&7)
        const int base = ((h >> 4) * 512) + ((h & 15) * 8) + (t >> 8) * 256;
        #pragma unroll
        for (int q = 0; q < 2; ++q) {
            union { int4v i; short8 s; } u;
            #pragma unroll
            for (int e = 0; e < 4; ++e)
                u.i[e] = pkbf(w[q * 8 + 2 * e], w[q * 8 + 2 * e + 1]);
            *(short8*)&ldsB[base + q * 128] = u.s;
        }
    }

    __syncthreads();

    // ---- 4) Compute: 8 tile-pairs, fc1 bias in MFMA C-init, fc2 folded in ----
    float pacc[4][2];
    #pragma unroll
    for (int r = 0; r < 4; ++r)
        pacc[r][0] = pacc[r][1] = 0.0f;

    #pragma unroll
    for (int p = 0; p < 8; ++p) {
        short8 bfA = *(short8*)&ldsB[(p * 64 + lane) * 8];
        short8 bfB = *(short8*)&ldsB[((p + 8) * 64 + lane) * 8];
        float4 prm = ldsP[p * 16 + m];   // {bias_a, bias_b, w2a, w2b} for h=p*16+m
        floatx4 ca = {prm.x, prm.x, prm.x, prm.x};   // per-col fc1 bias as C-init
        floatx4 cb = {prm.y, prm.y, prm.y, prm.y};

        floatx4 xa = __builtin_amdgcn_mfma_f32_16x16x32_bf16(afrag, bfA, ca, 0, 0, 0);
        floatx4 xb = __builtin_amdgcn_mfma_f32_16x16x32_bf16(afrag, bfB, cb, 0, 0, 0);
        #pragma unroll
        for (int r = 0; r < 4; ++r) {
            float glu = xa[r] * sigmoidf_(xb[r]);
            pacc[r][0] += glu * prm.z;
            pacc[r][1] += glu * prm.w;
        }
    }

    // ---- 5) Reduce fc2 partials across the 16 lanes of each quad ----
    #pragma unroll
    for (int r = 0; r < 4; ++r) {
        float s0 = pacc[r][0];
        float s1 = pacc[r][1];
        s0 += __shfl_xor(s0, 1);  s1 += __shfl_xor(s1, 1);
        s0 += __shfl_xor(s0, 2);  s1 += __shfl_xor(s1, 2);
        s0 += __shfl_xor(s0, 4);  s1 += __shfl_xor(s1, 4);
        s0 += __shfl_xor(s0, 8);  s1 += __shfl_xor(s1, 8);
        if (m == 0) {
            const int b = wv * 16 + quad * 4 + r;
            float x0 = s0 + bb0;
            float x1 = s1 + bb1;
            ldsO[b] = x0 * sigmoidf_(x1) * invT;
        }
    }

    __syncthreads();

    // One coalesced 512B row per block into out_t (2048,128).
    if (t < 128)
        out_t[(size_t)n * 128 + t] = ldsO[t];
}

// Transpose out_t (2048,128) -> out (128,2048). 32x32 tiles, 256 blocks.
__global__ __launch_bounds__(256)
void transpose_kernel(const float* __restrict__ out_t, float* __restrict__ out)
{
    __shared__ float tile[32][33];
    const int t    = threadIdx.x;
    const int bidx = blockIdx.x;           // 0..255
    const int n0   = (bidx & 63) * 32;     // 64 n-tiles
    const int b0   = (bidx >> 6) * 32;     // 4 b-tiles

    const int tx = t & 31;
    const int ty = t >> 5;                 // 0..7

    #pragma unroll
    for (int i = 0; i < 4; ++i) {
        const int nl = ty + i * 8;
        tile[nl][tx] = out_t[(size_t)(n0 + nl) * 128 + b0 + tx];
    }

    __syncthreads();

    #pragma unroll
    for (int i = 0; i < 4; ++i) {
        const int bl = ty + i * 8;
        out[(size_t)(b0 + bl) * NN + n0 + tx] = tile[tx][bl];
    }
}

extern "C" void kernel_launch(void* const* d_in, const int* in_sizes, int n_in,
                              void* d_out, int out_size, void* d_ws, size_t ws_size,
                              hipStream_t stream) {
    const float* st = (const float*)d_in[0];
    const float* w1 = (const float*)d_in[1];
    const float* b1 = (const float*)d_in[2];
    const float* w2 = (const float*)d_in[3];
    const float* b2 = (const float*)d_in[4];
    const float* T  = (const float*)d_in[5];
    float* out   = (float*)d_out;
    float* out_t = (float*)d_ws;    // 2048*128*4 = 1 MB scratch

    nlm_kernel<<<dim3(NN), dim3(512), 0, stream>>>(st, w1, b1, w2, b2, T, out_t);
    transpose_kernel<<<dim3(256), dim3(256), 0, stream>>>(out_t, out);
}